// Round 9
// baseline (2544.016 us; speedup 1.0000x reference)
//
#include <hip/hip_runtime.h>

// ConvLSTM2D via MFMA implicit-GEMM. B=8,T=16,H=W=64,Cin=32,F=64,3x3 SAME.
// Round 9: PERSISTENT kernel with hand-rolled grid barrier (plain launch;
// R8's hipLaunchCooperativeKernel never ran). All 16 timesteps in one
// kernel; per-step counter barrier in ws (device-scope atomics + s_sleep).
// Co-residency by construction: LDS 22.4KB/block (7/CU cap), VGPR<=256 via
// waves_per_eu(2,2) (2 blocks/CU cap) -> 512 blocks = 2/CU exactly resident.
//   - c-state in REGISTERS (16 floats/thread; same (px,ch) all steps)
//   - addressing/bias/frag bases computed once, reused 16 steps
//   - h ping-pongs bf16 in ws; only t=15 writes d_out (fp32)
//   - x staged fp32->bf16 in-kernel (ws stays 8.8 MB — R8's 41 MB was a
//     suspect); barrier counters zeroed by init kernel every launch
// Per block: 8x8 px tile x 256 z-ch, 4 waves; wave w owns n-tiles
// {w,w+4,w+8,w+12} so gates i/f/c/o of channel w*16+col share lane/reg
// (shuffle-free epilogue). A halos in LDS bf16 (pad 40/72, 2-way = free).
// Weights prepacked [s(27)][nt(16)][lane(64)][8] (442 KB, L2-resident).

#define TSTEPS 16
#define NBLK   512

typedef short bf16x8 __attribute__((ext_vector_type(8)));
typedef float f32x4 __attribute__((ext_vector_type(4)));

__device__ __forceinline__ float hsig(float x) {
    return fminf(fmaxf((x + 3.0f) * (1.0f / 6.0f), 0.0f), 1.0f);
}

__device__ __forceinline__ unsigned short f2bf(float f) {
    union { float f; unsigned int u; } v; v.f = f;
    unsigned int r = v.u + 0x7fffu + ((v.u >> 16) & 1u);  // RNE
    return (unsigned short)(r >> 16);
}

// ---- zero the barrier counters (ws is re-poisoned 0xAA before each call) ----
__global__ void init_bar(unsigned* __restrict__ bar) {
    if (threadIdx.x < 32) bar[threadIdx.x] = 0u;
}

// ---- weight prepack: Wg(3,3,32,256), Ug(3,3,64,256) fp32 -> bf16 B-frags ----
__global__ __launch_bounds__(256)
void prepack_w(const float* __restrict__ Wg, const float* __restrict__ Ug,
               unsigned short* __restrict__ out)
{
    int idx = blockIdx.x * 256 + threadIdx.x;   // 27*16*64 = 27648
    if (idx >= 27648) return;
    int lane = idx & 63;
    int nt   = (idx >> 6) & 15;
    int s    = idx >> 10;
    int col = lane & 15, quad = lane >> 4;
    int n = nt * 16 + col;
    int k0 = quad * 8;
    const float* src;
    if (s < 9) {
        src = Wg + ((size_t)s * 32 + k0) * 256 + n;
    } else {
        int ss = s - 9; int tap = ss >> 1; int half = ss & 1;
        src = Ug + ((size_t)tap * 64 + half * 32 + k0) * 256 + n;
    }
    unsigned short tmp[8];
    #pragma unroll
    for (int j = 0; j < 8; ++j) tmp[j] = f2bf(src[(size_t)j * 256]);
    *(uint4*)(out + (size_t)idx * 8) = *(uint4*)tmp;
}

// ---- persistent ConvLSTM: all 16 steps, global barrier between ----
__global__ __launch_bounds__(256)
__attribute__((amdgpu_waves_per_eu(2, 2)))
void convlstm_all(const float* __restrict__ x,        // (B,T,64,64,32) fp32
                  const unsigned short* __restrict__ wpk,
                  const float* __restrict__ bias,     // (256)
                  unsigned short* __restrict__ hA,    // bf16 ping
                  unsigned short* __restrict__ hB,    // bf16 pong
                  float* __restrict__ out,            // (B,64,64,64) fp32
                  unsigned* __restrict__ bar)         // [16] step counters
{
    __shared__ __align__(16) unsigned short xs_s[100 * 40];  //  8.0 KB
    __shared__ __align__(16) unsigned short hs_s[100 * 72];  // 14.4 KB

    const int tid = threadIdx.x;
    const int blk = blockIdx.x;                // 0..511
    const int gx0 = (blk & 7) * 8;
    const int gy0 = ((blk >> 3) & 7) * 8;
    const int b   = blk >> 6;

    const int lane = tid & 63;
    const int w    = tid >> 6;
    const int quad = lane >> 4;
    const int m    = lane & 15;
    const int ch   = w * 16 + m;               // output channel 0..63

    int xb[4], hb_[4];
    #pragma unroll
    for (int mt = 0; mt < 4; ++mt) {
        int p = mt * 16 + m;
        int py = p >> 3, px = p & 7;
        xb[mt]  = (py * 10 + px) * 40 + quad * 8;
        hb_[mt] = (py * 10 + px) * 72 + quad * 8;
    }
    const unsigned short* wb = wpk + ((size_t)w * 64 + lane) * 8;

    float bv[4];
    #pragma unroll
    for (int g = 0; g < 4; ++g) bv[g] = bias[g * 64 + ch];

    // cell state in registers: [mt][r] for this thread's (pixel, channel)
    float cr[4][4];
    #pragma unroll
    for (int mt = 0; mt < 4; ++mt)
        #pragma unroll
        for (int r = 0; r < 4; ++r) cr[mt][r] = 0.0f;

    const unsigned short* hin  = hB;   // not read at t=0
    unsigned short*       hout = hA;

    #pragma unroll 1
    for (int t = 0; t < TSTEPS; ++t) {
        // ---- stage x halo (fp32 -> bf16): 100 px * 8 float4 chunks ----
        {
            const float* xt = x + (((size_t)b * TSTEPS + t) * (size_t)(64 * 64 * 32));
            #pragma unroll
            for (int idx = tid; idx < 100 * 8; idx += 256) {
                int pix = idx >> 3, q = idx & 7;
                int iy = pix / 10, ix = pix - iy * 10;
                int gy = gy0 + iy - 1, gx = gx0 + ix - 1;
                unsigned short o[4] = {0, 0, 0, 0};
                if ((unsigned)gy < 64u && (unsigned)gx < 64u) {
                    float4 v = *(const float4*)(xt + ((size_t)(gy * 64 + gx) * 32) + q * 4);
                    o[0] = f2bf(v.x); o[1] = f2bf(v.y); o[2] = f2bf(v.z); o[3] = f2bf(v.w);
                }
                *(ushort4*)(xs_s + pix * 40 + q * 4) = *(ushort4*)o;
            }
        }
        // ---- stage h halo (bf16 copy): 100 px * 8 chunks of 8 ----
        if (t > 0) {
            const unsigned short* hbp = hin + ((size_t)b * (64 * 64 * 64));
            #pragma unroll
            for (int idx = tid; idx < 100 * 8; idx += 256) {
                int pix = idx >> 3, q = idx & 7;
                int iy = pix / 10, ix = pix - iy * 10;
                int gy = gy0 + iy - 1, gx = gx0 + ix - 1;
                uint4 v = make_uint4(0u, 0u, 0u, 0u);
                if ((unsigned)gy < 64u && (unsigned)gx < 64u)
                    v = *(const uint4*)(hbp + ((size_t)(gy * 64 + gx) * 64) + q * 8);
                *(uint4*)(hs_s + pix * 72 + q * 8) = v;
            }
        }
        __syncthreads();

        f32x4 acc[4][4];   // [mt][gate]
        #pragma unroll
        for (int g = 0; g < 4; ++g) {
            f32x4 bi = (f32x4){bv[g], bv[g], bv[g], bv[g]};
            #pragma unroll
            for (int mt = 0; mt < 4; ++mt) acc[mt][g] = bi;
        }

        auto body = [&](int s) {
            bf16x8 a[4];
            if (s < 9) {
                int taplin = (s / 3) * 10 + (s % 3);
                #pragma unroll
                for (int mt = 0; mt < 4; ++mt)
                    a[mt] = *(const bf16x8*)(xs_s + xb[mt] + taplin * 40);
            } else {
                int ss = s - 9, tap = ss >> 1, half = ss & 1;
                int taplin = (tap / 3) * 10 + (tap % 3);
                #pragma unroll
                for (int mt = 0; mt < 4; ++mt)
                    a[mt] = *(const bf16x8*)(hs_s + hb_[mt] + taplin * 72 + half * 32);
            }
            #pragma unroll
            for (int g = 0; g < 4; ++g) {
                bf16x8 bf = *(const bf16x8*)(wb + (size_t)(s * 16 + 4 * g) * 512);
                #pragma unroll
                for (int mt = 0; mt < 4; ++mt)
                    acc[mt][g] = __builtin_amdgcn_mfma_f32_16x16x32_bf16(a[mt], bf, acc[mt][g], 0, 0, 0);
            }
        };

        if (t == 0) {
            #pragma unroll
            for (int s = 0; s < 9; ++s) body(s);
        } else {
            #pragma unroll
            for (int s = 0; s < 27; ++s) body(s);
        }

        // ---- epilogue: gates + in-register c update ----
        #pragma unroll
        for (int mt = 0; mt < 4; ++mt) {
            #pragma unroll
            for (int r = 0; r < 4; ++r) {
                int p = mt * 16 + quad * 4 + r;
                int py = p >> 3, px = p & 7;
                size_t gidx = (((size_t)b * 64 + (gy0 + py)) * 64 + (gx0 + px)) * 64 + ch;
                float zi = acc[mt][0][r];
                float zf = acc[mt][1][r];
                float zc = acc[mt][2][r];
                float zo = acc[mt][3][r];
                float cn = hsig(zf) * cr[mt][r] + hsig(zi) * fmaxf(zc, 0.0f);
                float hn = hsig(zo) * fmaxf(cn, 0.0f);
                cr[mt][r] = cn;
                if (t == TSTEPS - 1) out[gidx] = hn;
                else                 hout[gidx] = f2bf(hn);
            }
        }

        // ---- grid barrier (except after the last step) ----
        if (t < TSTEPS - 1) {
            __threadfence();            // release h-writes to device scope
            __syncthreads();            // all waves of this block arrived
            if (tid == 0) {
                atomicAdd(&bar[t], 1u);
                while (atomicAdd(&bar[t], 0u) < (unsigned)NBLK)
                    __builtin_amdgcn_s_sleep(2);
            }
            __syncthreads();            // block released
            __threadfence();            // acquire: invalidate L1 (hin re-read)
            const unsigned short* nin = hout;
            hout = (hout == hA) ? hB : hA;
            hin  = nin;
        }
    }
}

extern "C" void kernel_launch(void* const* d_in, const int* in_sizes, int n_in,
                              void* d_out, int out_size, void* d_ws, size_t ws_size,
                              hipStream_t stream) {
    const float* x  = (const float*)d_in[0];
    const float* Wg = (const float*)d_in[1];
    const float* Ug = (const float*)d_in[2];
    const float* bs = (const float*)d_in[3];

    // ws layout: [wpk 442368 B][bar 128 B][hA 4 MB][hB 4 MB]   (~8.8 MB)
    unsigned short* wpk = (unsigned short*)d_ws;
    unsigned*       bar = (unsigned*)((char*)d_ws + 442368);
    unsigned short* hA  = (unsigned short*)((char*)d_ws + 442368 + 128);
    unsigned short* hB  = hA + (size_t)8 * 64 * 64 * 64;
    float* outp = (float*)d_out;

    init_bar<<<1, 64, 0, stream>>>(bar);
    prepack_w<<<108, 256, 0, stream>>>(Wg, Ug, wpk);
    convlstm_all<<<NBLK, 256, 0, stream>>>(x, wpk, bs, hA, hB, outp, bar);
}

// Round 11
// 2352.751 us; speedup vs baseline: 1.0813x; 1.0813x over previous
//
#include <hip/hip_runtime.h>

// ConvLSTM2D via MFMA implicit-GEMM. B=8,T=16,H=W=64,Cin=32,F=64,3x3 SAME.
// Round 11 (= R10 + pragma-placement fix): persistent kernel, FIXED grid
// barrier. R9's barrier polled with device-scope atomic RMW from 512 blocks
// -> coherence-point storm (FETCH 783 MB, ~150us/barrier). Fix: arrival =
// ONE relaxed fetch_add per block; poll = read-only agent-scope atomic load
// + s_sleep backoff.
// Post-barrier critical path shortened:
//   - x(t+1) staged BEFORE the barrier (overlaps the wait)
//   - h halo interior (64/100 px) written to LDS by own epilogue; only the
//     36-px ring is read from global after the barrier
//   - h global writes: edge pixels only (28/64) -> less dirty L2 at the fence
//   - c-state in registers; bias/addressing hoisted out of the t-loop
// Per block: 8x8 px tile x 256 z-ch, 4 waves; wave w owns n-tiles
// {w,w+4,w+8,w+12} (shuffle-free gate epilogue). A halos LDS bf16 (pad 40/72).
// Weights prepacked [s(27)][nt(16)][lane(64)][8] (442 KB, L2-resident).
// 512 blocks = 2/CU exactly co-resident (LDS 22.4KB, waves_per_eu(2,2)).

#define TSTEPS 16
#define NBLK   512

typedef short bf16x8 __attribute__((ext_vector_type(8)));
typedef float f32x4 __attribute__((ext_vector_type(4)));

__device__ __forceinline__ float hsig(float x) {
    return fminf(fmaxf((x + 3.0f) * (1.0f / 6.0f), 0.0f), 1.0f);
}

__device__ __forceinline__ unsigned short f2bf(float f) {
    union { float f; unsigned int u; } v; v.f = f;
    unsigned int r = v.u + 0x7fffu + ((v.u >> 16) & 1u);  // RNE
    return (unsigned short)(r >> 16);
}

__global__ void init_bar(unsigned* __restrict__ bar) {
    if (threadIdx.x < 32) bar[threadIdx.x] = 0u;
}

// ---- weight prepack: Wg(3,3,32,256), Ug(3,3,64,256) fp32 -> bf16 B-frags ----
__global__ __launch_bounds__(256)
void prepack_w(const float* __restrict__ Wg, const float* __restrict__ Ug,
               unsigned short* __restrict__ out)
{
    int idx = blockIdx.x * 256 + threadIdx.x;   // 27*16*64 = 27648
    if (idx >= 27648) return;
    int lane = idx & 63;
    int nt   = (idx >> 6) & 15;
    int s    = idx >> 10;
    int col = lane & 15, quad = lane >> 4;
    int n = nt * 16 + col;
    int k0 = quad * 8;
    const float* src;
    if (s < 9) {
        src = Wg + ((size_t)s * 32 + k0) * 256 + n;
    } else {
        int ss = s - 9; int tap = ss >> 1; int half = ss & 1;
        src = Ug + ((size_t)tap * 64 + half * 32 + k0) * 256 + n;
    }
    unsigned short tmp[8];
    #pragma unroll
    for (int j = 0; j < 8; ++j) tmp[j] = f2bf(src[(size_t)j * 256]);
    *(uint4*)(out + (size_t)idx * 8) = *(uint4*)tmp;
}

// ---- persistent ConvLSTM: all 16 steps, cheap global barrier between ----
__global__ __launch_bounds__(256)
__attribute__((amdgpu_waves_per_eu(2, 2)))
void convlstm_all(const float* __restrict__ x,        // (B,T,64,64,32) fp32
                  const unsigned short* __restrict__ wpk,
                  const float* __restrict__ bias,     // (256)
                  unsigned short* __restrict__ hA,    // bf16 ping (edges)
                  unsigned short* __restrict__ hB,    // bf16 pong (edges)
                  float* __restrict__ out,            // (B,64,64,64) fp32
                  unsigned* __restrict__ bar)         // [16] step counters
{
    __shared__ __align__(16) unsigned short xs_s[100 * 40];  //  8.0 KB
    __shared__ __align__(16) unsigned short hs_s[100 * 72];  // 14.4 KB

    const int tid = threadIdx.x;
    const int blk = blockIdx.x;                // 0..511
    const int gx0 = (blk & 7) * 8;
    const int gy0 = ((blk >> 3) & 7) * 8;
    const int b   = blk >> 6;

    const int lane = tid & 63;
    const int w    = tid >> 6;
    const int quad = lane >> 4;
    const int m    = lane & 15;
    const int ch   = w * 16 + m;               // output channel 0..63

    int xb[4], hb_[4];
    #pragma unroll
    for (int mt = 0; mt < 4; ++mt) {
        int p = mt * 16 + m;
        int py = p >> 3, px = p & 7;
        xb[mt]  = (py * 10 + px) * 40 + quad * 8;
        hb_[mt] = (py * 10 + px) * 72 + quad * 8;
    }
    const unsigned short* wb = wpk + ((size_t)w * 64 + lane) * 8;

    float bv[4];
    #pragma unroll
    for (int g = 0; g < 4; ++g) bv[g] = bias[g * 64 + ch];

    float cr[4][4];            // cell state in registers
    #pragma unroll
    for (int mt = 0; mt < 4; ++mt)
        #pragma unroll
        for (int r = 0; r < 4; ++r) cr[mt][r] = 0.0f;

    const unsigned short* hin  = hB;
    unsigned short*       hout = hA;

    // ---- x staging helper (fp32 -> bf16 into xs_s) ----
    auto stage_x = [&](int t) {
        const float* xt = x + (((size_t)b * TSTEPS + t) * (size_t)(64 * 64 * 32));
        #pragma unroll
        for (int idx = tid; idx < 100 * 8; idx += 256) {
            int pix = idx >> 3, q = idx & 7;
            int iy = pix / 10, ix = pix - iy * 10;
            int gy = gy0 + iy - 1, gx = gx0 + ix - 1;
            unsigned short o[4] = {0, 0, 0, 0};
            if ((unsigned)gy < 64u && (unsigned)gx < 64u) {
                float4 v = *(const float4*)(xt + ((size_t)(gy * 64 + gx) * 32) + q * 4);
                o[0] = f2bf(v.x); o[1] = f2bf(v.y); o[2] = f2bf(v.z); o[3] = f2bf(v.w);
            }
            *(ushort4*)(xs_s + pix * 40 + q * 4) = *(ushort4*)o;
        }
    };

    stage_x(0);
    __syncthreads();

    #pragma unroll 1
    for (int t = 0; t < TSTEPS; ++t) {
        // ---- K-loop ----
        f32x4 acc[4][4];
        #pragma unroll
        for (int g = 0; g < 4; ++g) {
            f32x4 bi = (f32x4){bv[g], bv[g], bv[g], bv[g]};
            #pragma unroll
            for (int mt = 0; mt < 4; ++mt) acc[mt][g] = bi;
        }
        auto body = [&](int s) {
            bf16x8 a[4];
            if (s < 9) {
                int taplin = (s / 3) * 10 + (s % 3);
                #pragma unroll
                for (int mt = 0; mt < 4; ++mt)
                    a[mt] = *(const bf16x8*)(xs_s + xb[mt] + taplin * 40);
            } else {
                int ss = s - 9, tap = ss >> 1, half = ss & 1;
                int taplin = (tap / 3) * 10 + (tap % 3);
                #pragma unroll
                for (int mt = 0; mt < 4; ++mt)
                    a[mt] = *(const bf16x8*)(hs_s + hb_[mt] + taplin * 72 + half * 32);
            }
            #pragma unroll
            for (int g = 0; g < 4; ++g) {
                bf16x8 bf = *(const bf16x8*)(wb + (size_t)(s * 16 + 4 * g) * 512);
                #pragma unroll
                for (int mt = 0; mt < 4; ++mt)
                    acc[mt][g] = __builtin_amdgcn_mfma_f32_16x16x32_bf16(a[mt], bf, acc[mt][g], 0, 0, 0);
            }
        };
        if (t == 0) {
            #pragma unroll
            for (int s = 0; s < 9; ++s) body(s);
        } else {
            #pragma unroll
            for (int s = 0; s < 27; ++s) body(s);
        }

        // ---- gate math, c update in registers ----
        float hnv[4][4];
        #pragma unroll
        for (int mt = 0; mt < 4; ++mt)
            #pragma unroll
            for (int r = 0; r < 4; ++r) {
                float zi = acc[mt][0][r];
                float zf = acc[mt][1][r];
                float zc = acc[mt][2][r];
                float zo = acc[mt][3][r];
                float cn = hsig(zf) * cr[mt][r] + hsig(zi) * fmaxf(zc, 0.0f);
                float hn = hsig(zo) * fmaxf(cn, 0.0f);
                cr[mt][r] = cn;
                hnv[mt][r] = hn;
            }

        if (t == TSTEPS - 1) {
            // final step: write full h fp32 to d_out, done
            #pragma unroll
            for (int mt = 0; mt < 4; ++mt)
                #pragma unroll
                for (int r = 0; r < 4; ++r) {
                    int p = mt * 16 + quad * 4 + r;
                    int py = p >> 3, px = p & 7;
                    size_t gidx = (((size_t)b * 64 + (gy0 + py)) * 64 + (gx0 + px)) * 64 + ch;
                    out[gidx] = hnv[mt][r];
                }
            break;
        }

        __syncthreads();   // all waves done reading xs_s/hs_s

        // ---- publish h(t): LDS interior (own next step) + global edges
        //      (neighbors' rings); prefetch x(t+1) before the barrier ----
        #pragma unroll
        for (int mt = 0; mt < 4; ++mt)
            #pragma unroll
            for (int r = 0; r < 4; ++r) {
                int p = mt * 16 + quad * 4 + r;
                int py = p >> 3, px = p & 7;
                unsigned short hb16 = f2bf(hnv[mt][r]);
                hs_s[((py + 1) * 10 + (px + 1)) * 72 + ch] = hb16;
                if (py == 0 || py == 7 || px == 0 || px == 7) {
                    size_t gidx = (((size_t)b * 64 + (gy0 + py)) * 64 + (gx0 + px)) * 64 + ch;
                    hout[gidx] = hb16;
                }
            }
        stage_x(t + 1);

        // ---- grid barrier: 1 RMW arrival, read-only poll w/ backoff ----
        __threadfence();               // release h-edge writes
        __syncthreads();
        if (tid == 0) {
            __hip_atomic_fetch_add(&bar[t], 1u, __ATOMIC_RELAXED,
                                   __HIP_MEMORY_SCOPE_AGENT);
            while (__hip_atomic_load(&bar[t], __ATOMIC_RELAXED,
                                     __HIP_MEMORY_SCOPE_AGENT) < (unsigned)NBLK)
                __builtin_amdgcn_s_sleep(8);
        }
        __syncthreads();
        __threadfence();               // acquire: invalidate L1 for ring reads

        const unsigned short* nin = hout;
        hout = (hout == hA) ? hB : hA;
        hin  = nin;

        // ---- stage the 36-px h ring from neighbors ----
        {
            const unsigned short* hbp = hin + ((size_t)b * (64 * 64 * 64));
            #pragma unroll
            for (int idx = tid; idx < 36 * 8; idx += 256) {
                int rp = idx >> 3, q = idx & 7;
                int iy, ix;
                if (rp < 10)      { iy = 0;       ix = rp; }
                else if (rp < 20) { iy = 9;       ix = rp - 10; }
                else if (rp < 28) { iy = rp - 19; ix = 0; }
                else              { iy = rp - 27; ix = 9; }
                int gy = gy0 + iy - 1, gx = gx0 + ix - 1;
                uint4 v = make_uint4(0u, 0u, 0u, 0u);
                if ((unsigned)gy < 64u && (unsigned)gx < 64u)
                    v = *(const uint4*)(hbp + ((size_t)(gy * 64 + gx) * 64) + q * 8);
                *(uint4*)(hs_s + (iy * 10 + ix) * 72 + q * 8) = v;
            }
        }
        __syncthreads();
    }
}

extern "C" void kernel_launch(void* const* d_in, const int* in_sizes, int n_in,
                              void* d_out, int out_size, void* d_ws, size_t ws_size,
                              hipStream_t stream) {
    const float* x  = (const float*)d_in[0];
    const float* Wg = (const float*)d_in[1];
    const float* Ug = (const float*)d_in[2];
    const float* bs = (const float*)d_in[3];

    // ws layout: [wpk 442368 B][bar 128 B][hA 4 MB][hB 4 MB]   (~8.8 MB)
    unsigned short* wpk = (unsigned short*)d_ws;
    unsigned*       bar = (unsigned*)((char*)d_ws + 442368);
    unsigned short* hA  = (unsigned short*)((char*)d_ws + 442368 + 128);
    unsigned short* hB  = hA + (size_t)8 * 64 * 64 * 64;
    float* outp = (float*)d_out;

    init_bar<<<1, 64, 0, stream>>>(bar);
    prepack_w<<<108, 256, 0, stream>>>(Wg, Ug, wpk);
    convlstm_all<<<NBLK, 256, 0, stream>>>(x, wpk, bs, hA, hB, outp, bar);
}

// Round 12
// 1020.917 us; speedup vs baseline: 2.4919x; 2.3045x over previous
//
#include <hip/hip_runtime.h>

// ConvLSTM2D via MFMA implicit-GEMM. B=8,T=16,H=W=64,Cin=32,F=64,3x3 SAME.
// Round 12: persistent kernel, HIERARCHICAL barrier + fence-free exchange.
// R9/R11 post-mortem: 512 same-line pollers serialize at the coherence
// point (~200ns each -> ~100us queue = the 150us/barrier), and per-step
// __threadfence() flushed/invalidated L2 (weight set evicted every step).
// Fixes:
//   - tree barrier: 64 leaf counters (8 blocks each, 128B apart) -> root ->
//     per-leaf go words; pollers poll ONLY their leaf's go line (8/line),
//     s_sleep(32) backoff. Counters accumulate; no reset.
//   - NO __threadfence anywhere: h edges (3.6KB/block) move via agent-scope
//     relaxed atomic stores; ring read via agent-scope 8B atomic loads
//     (L1/L2-bypass, coherent at Infinity Cache). __syncthreads drains
//     vmcnt per wave before arrival => release ordering. L2 weights stay hot.
//   - x(t+1) staged before the barrier; h interior via LDS (own epilogue);
//     c-state in registers.
// Per block: 8x8 px tile x 256 z-ch, 4 waves; wave w owns n-tiles
// {w,w+4,w+8,w+12} (shuffle-free gate epilogue). A halos LDS bf16 (pad 40/72).
// Weights prepacked [s(27)][nt(16)][lane(64)][8] (442 KB, L2-resident).
// 512 blocks = 2/CU exactly co-resident (LDS 22.4KB, waves_per_eu(2,2)).

#define TSTEPS 16
#define NBLK   512

typedef short bf16x8 __attribute__((ext_vector_type(8)));
typedef float f32x4 __attribute__((ext_vector_type(4)));

__device__ __forceinline__ float hsig(float x) {
    return fminf(fmaxf((x + 3.0f) * (1.0f / 6.0f), 0.0f), 1.0f);
}

__device__ __forceinline__ unsigned short f2bf(float f) {
    union { float f; unsigned int u; } v; v.f = f;
    unsigned int r = v.u + 0x7fffu + ((v.u >> 16) & 1u);  // RNE
    return (unsigned short)(r >> 16);
}

// bar layout (words): [0..2047] leaf counters (leaf*32), [2048..4095] go
// words (2048+leaf*32), [4096] root. 16.4 KB, zeroed every launch.
__global__ __launch_bounds__(256)
void init_bar(unsigned* __restrict__ bar) {
    for (int i = threadIdx.x; i < 4160; i += 256) bar[i] = 0u;
}

// ---- weight prepack: Wg(3,3,32,256), Ug(3,3,64,256) fp32 -> bf16 B-frags ----
__global__ __launch_bounds__(256)
void prepack_w(const float* __restrict__ Wg, const float* __restrict__ Ug,
               unsigned short* __restrict__ out)
{
    int idx = blockIdx.x * 256 + threadIdx.x;   // 27*16*64 = 27648
    if (idx >= 27648) return;
    int lane = idx & 63;
    int nt   = (idx >> 6) & 15;
    int s    = idx >> 10;
    int col = lane & 15, quad = lane >> 4;
    int n = nt * 16 + col;
    int k0 = quad * 8;
    const float* src;
    if (s < 9) {
        src = Wg + ((size_t)s * 32 + k0) * 256 + n;
    } else {
        int ss = s - 9; int tap = ss >> 1; int half = ss & 1;
        src = Ug + ((size_t)tap * 64 + half * 32 + k0) * 256 + n;
    }
    unsigned short tmp[8];
    #pragma unroll
    for (int j = 0; j < 8; ++j) tmp[j] = f2bf(src[(size_t)j * 256]);
    *(uint4*)(out + (size_t)idx * 8) = *(uint4*)tmp;
}

// ---- persistent ConvLSTM: all 16 steps, tree barrier between ----
__global__ __launch_bounds__(256)
__attribute__((amdgpu_waves_per_eu(2, 2)))
void convlstm_all(const float* __restrict__ x,        // (B,T,64,64,32) fp32
                  const unsigned short* __restrict__ wpk,
                  const float* __restrict__ bias,     // (256)
                  unsigned short* __restrict__ hA,    // bf16 ping (edges)
                  unsigned short* __restrict__ hB,    // bf16 pong (edges)
                  float* __restrict__ out,            // (B,64,64,64) fp32
                  unsigned* __restrict__ bar)
{
    __shared__ __align__(16) unsigned short xs_s[100 * 40];  //  8.0 KB
    __shared__ __align__(16) unsigned short hs_s[100 * 72];  // 14.4 KB

    const int tid = threadIdx.x;
    const int blk = blockIdx.x;                // 0..511
    const int gx0 = (blk & 7) * 8;
    const int gy0 = ((blk >> 3) & 7) * 8;
    const int b   = blk >> 6;
    const unsigned leaf = (unsigned)blk >> 3;  // 0..63

    const int lane = tid & 63;
    const int w    = tid >> 6;
    const int quad = lane >> 4;
    const int m    = lane & 15;
    const int ch   = w * 16 + m;               // output channel 0..63

    int xb[4], hb_[4];
    #pragma unroll
    for (int mt = 0; mt < 4; ++mt) {
        int p = mt * 16 + m;
        int py = p >> 3, px = p & 7;
        xb[mt]  = (py * 10 + px) * 40 + quad * 8;
        hb_[mt] = (py * 10 + px) * 72 + quad * 8;
    }
    const unsigned short* wb = wpk + ((size_t)w * 64 + lane) * 8;

    float bv[4];
    #pragma unroll
    for (int g = 0; g < 4; ++g) bv[g] = bias[g * 64 + ch];

    float cr[4][4];            // cell state in registers
    #pragma unroll
    for (int mt = 0; mt < 4; ++mt)
        #pragma unroll
        for (int r = 0; r < 4; ++r) cr[mt][r] = 0.0f;

    const unsigned short* hin  = hB;
    unsigned short*       hout = hA;

    auto stage_x = [&](int t) {
        const float* xt = x + (((size_t)b * TSTEPS + t) * (size_t)(64 * 64 * 32));
        #pragma unroll
        for (int idx = tid; idx < 100 * 8; idx += 256) {
            int pix = idx >> 3, q = idx & 7;
            int iy = pix / 10, ix = pix - iy * 10;
            int gy = gy0 + iy - 1, gx = gx0 + ix - 1;
            unsigned short o[4] = {0, 0, 0, 0};
            if ((unsigned)gy < 64u && (unsigned)gx < 64u) {
                float4 v = *(const float4*)(xt + ((size_t)(gy * 64 + gx) * 32) + q * 4);
                o[0] = f2bf(v.x); o[1] = f2bf(v.y); o[2] = f2bf(v.z); o[3] = f2bf(v.w);
            }
            *(ushort4*)(xs_s + pix * 40 + q * 4) = *(ushort4*)o;
        }
    };

    stage_x(0);
    __syncthreads();

    #pragma unroll 1
    for (int t = 0; t < TSTEPS; ++t) {
        // ---- K-loop ----
        f32x4 acc[4][4];
        #pragma unroll
        for (int g = 0; g < 4; ++g) {
            f32x4 bi = (f32x4){bv[g], bv[g], bv[g], bv[g]};
            #pragma unroll
            for (int mt = 0; mt < 4; ++mt) acc[mt][g] = bi;
        }
        auto body = [&](int s) {
            bf16x8 a[4];
            if (s < 9) {
                int taplin = (s / 3) * 10 + (s % 3);
                #pragma unroll
                for (int mt = 0; mt < 4; ++mt)
                    a[mt] = *(const bf16x8*)(xs_s + xb[mt] + taplin * 40);
            } else {
                int ss = s - 9, tap = ss >> 1, half = ss & 1;
                int taplin = (tap / 3) * 10 + (tap % 3);
                #pragma unroll
                for (int mt = 0; mt < 4; ++mt)
                    a[mt] = *(const bf16x8*)(hs_s + hb_[mt] + taplin * 72 + half * 32);
            }
            #pragma unroll
            for (int g = 0; g < 4; ++g) {
                bf16x8 bf = *(const bf16x8*)(wb + (size_t)(s * 16 + 4 * g) * 512);
                #pragma unroll
                for (int mt = 0; mt < 4; ++mt)
                    acc[mt][g] = __builtin_amdgcn_mfma_f32_16x16x32_bf16(a[mt], bf, acc[mt][g], 0, 0, 0);
            }
        };
        if (t == 0) {
            #pragma unroll
            for (int s = 0; s < 9; ++s) body(s);
        } else {
            #pragma unroll
            for (int s = 0; s < 27; ++s) body(s);
        }

        // ---- gate math, c update in registers ----
        float hnv[4][4];
        #pragma unroll
        for (int mt = 0; mt < 4; ++mt)
            #pragma unroll
            for (int r = 0; r < 4; ++r) {
                float zi = acc[mt][0][r];
                float zf = acc[mt][1][r];
                float zc = acc[mt][2][r];
                float zo = acc[mt][3][r];
                float cn = hsig(zf) * cr[mt][r] + hsig(zi) * fmaxf(zc, 0.0f);
                float hn = hsig(zo) * fmaxf(cn, 0.0f);
                cr[mt][r] = cn;
                hnv[mt][r] = hn;
            }

        if (t == TSTEPS - 1) {
            #pragma unroll
            for (int mt = 0; mt < 4; ++mt)
                #pragma unroll
                for (int r = 0; r < 4; ++r) {
                    int p = mt * 16 + quad * 4 + r;
                    int py = p >> 3, px = p & 7;
                    size_t gidx = (((size_t)b * 64 + (gy0 + py)) * 64 + (gx0 + px)) * 64 + ch;
                    out[gidx] = hnv[mt][r];
                }
            break;
        }

        __syncthreads();   // all waves done reading xs_s/hs_s of step t

        // ---- publish h(t): LDS interior + AGENT-scope atomic edge stores
        //      (L2-bypass, coherent at IF); prestage x(t+1) ----
        #pragma unroll
        for (int mt = 0; mt < 4; ++mt)
            #pragma unroll
            for (int r = 0; r < 4; ++r) {
                int p = mt * 16 + quad * 4 + r;
                int py = p >> 3, px = p & 7;
                unsigned short hb16 = f2bf(hnv[mt][r]);
                hs_s[((py + 1) * 10 + (px + 1)) * 72 + ch] = hb16;
                if (py == 0 || py == 7 || px == 0 || px == 7) {
                    size_t gidx = (((size_t)b * 64 + (gy0 + py)) * 64 + (gx0 + px)) * 64 + ch;
                    __hip_atomic_store(&hout[gidx], hb16, __ATOMIC_RELAXED,
                                       __HIP_MEMORY_SCOPE_AGENT);
                }
            }
        stage_x(t + 1);

        // ---- tree barrier (no fences; __syncthreads drains vmcnt/wave) ----
        __syncthreads();
        if (tid == 0) {
            unsigned old = __hip_atomic_fetch_add(&bar[leaf * 32], 1u,
                                                  __ATOMIC_RELAXED, __HIP_MEMORY_SCOPE_AGENT);
            if (old == 8u * (unsigned)(t + 1) - 1u) {          // leaf winner
                unsigned rold = __hip_atomic_fetch_add(&bar[4096], 1u,
                                                       __ATOMIC_RELAXED, __HIP_MEMORY_SCOPE_AGENT);
                if (rold == 64u * (unsigned)(t + 1) - 1u) {    // root winner
                    #pragma unroll 1
                    for (int i = 0; i < 64; ++i)
                        __hip_atomic_store(&bar[2048 + i * 32], (unsigned)(t + 1),
                                           __ATOMIC_RELAXED, __HIP_MEMORY_SCOPE_AGENT);
                }
            }
            while (__hip_atomic_load(&bar[2048 + leaf * 32], __ATOMIC_RELAXED,
                                     __HIP_MEMORY_SCOPE_AGENT) < (unsigned)(t + 1))
                __builtin_amdgcn_s_sleep(32);
        }
        __syncthreads();

        const unsigned short* nin = hout;
        hout = (hout == hA) ? hB : hA;
        hin  = nin;

        // ---- stage the 36-px h ring via agent-scope 8B atomic loads ----
        {
            const unsigned short* hbp = hin + ((size_t)b * (64 * 64 * 64));
            #pragma unroll
            for (int idx = tid; idx < 36 * 16; idx += 256) {
                int rp = idx >> 4, q = idx & 15;   // q: 8B chunk (4 ch)
                int iy, ix;
                if (rp < 10)      { iy = 0;       ix = rp; }
                else if (rp < 20) { iy = 9;       ix = rp - 10; }
                else if (rp < 28) { iy = rp - 19; ix = 0; }
                else              { iy = rp - 27; ix = 9; }
                int gy = gy0 + iy - 1, gx = gx0 + ix - 1;
                unsigned long long v = 0ull;
                if ((unsigned)gy < 64u && (unsigned)gx < 64u)
                    v = __hip_atomic_load(
                        (const unsigned long long*)(hbp + ((size_t)(gy * 64 + gx) * 64) + q * 4),
                        __ATOMIC_RELAXED, __HIP_MEMORY_SCOPE_AGENT);
                *(unsigned long long*)(hs_s + (iy * 10 + ix) * 72 + q * 4) = v;
            }
        }
        __syncthreads();
    }
}

extern "C" void kernel_launch(void* const* d_in, const int* in_sizes, int n_in,
                              void* d_out, int out_size, void* d_ws, size_t ws_size,
                              hipStream_t stream) {
    const float* x  = (const float*)d_in[0];
    const float* Wg = (const float*)d_in[1];
    const float* Ug = (const float*)d_in[2];
    const float* bs = (const float*)d_in[3];

    // ws layout: [wpk 442368 B][bar 32 KB][hA 4 MB][hB 4 MB]
    unsigned short* wpk = (unsigned short*)d_ws;
    unsigned*       bar = (unsigned*)((char*)d_ws + 442368);
    unsigned short* hA  = (unsigned short*)((char*)d_ws + 442368 + 32768);
    unsigned short* hB  = hA + (size_t)8 * 64 * 64 * 64;
    float* outp = (float*)d_out;

    init_bar<<<1, 256, 0, stream>>>(bar);
    prepack_w<<<108, 256, 0, stream>>>(Wg, Ug, wpk);
    convlstm_all<<<NBLK, 256, 0, stream>>>(x, wpk, bs, hA, hB, outp, bar);
}